// Round 5
// baseline (81.512 us; speedup 1.0000x reference)
//
#include <hip/hip_runtime.h>

// conv_capsules patch extraction — GATHER with NON-TEMPORAL stores.
// x: [B=8, H=64, W=64, C=16, D=16] f32 -> out: [B, OH=62, OW=62, KH=3, KW=3, C, D]
// out[b,oh,ow,kh,kw,c,d] = x[b,oh+kh,ow+kw,c,d]
//
// History: gather w/ cached stores = 566 MB HBM (write stream evicts the 33.5MB
// input from L2 -> 9x read amplification) @ 82us. Scatter = 317 MB but 1KB-
// scattered writes only sustain 5.3 TB/s @ 60us. This version: output-linear
// gather (streaming writes like the 6.9 TB/s fill) + `nt` stores (no L2
// write-allocate) so the active input window stays L2-resident and reads are
// absorbed. Expected ~317 MB HBM @ write-stream rate -> ~48us.

typedef float f32x4 __attribute__((ext_vector_type(4)));

constexpr int H  = 64;
constexpr int W  = 64;
constexpr int KH = 3;
constexpr int KW = 3;
constexpr int OH = H - KH + 1;  // 62
constexpr int OW = W - KW + 1;  // 62
constexpr int CD4 = 64;         // float4 per (c,d) pixel (256 floats)

__global__ __launch_bounds__(256) void conv_capsules_gather_nt_kernel(
    const f32x4* __restrict__ in, f32x4* __restrict__ out, int total4)
{
    const int stride = gridDim.x * blockDim.x;
    for (int i = blockIdx.x * blockDim.x + threadIdx.x; i < total4; i += stride) {
        const int lane = i & (CD4 - 1);   // float4 index within the 1KB pixel
        int t = i >> 6;                   // tile = (b,oh,ow,kh,kw)
        const int kw = t % KW; t /= KW;
        const int kh = t % KH; t /= KH;
        const int ow = t % OW; t /= OW;
        const int oh = t % OH; t /= OH;
        const int b  = t;
        const int h = oh + kh;
        const int w = ow + kw;
        const f32x4 v = in[((b * H + h) * W + w) * CD4 + lane];  // cached read (L2)
        __builtin_nontemporal_store(v, &out[i]);                  // nt write (no L2 alloc)
    }
}

extern "C" void kernel_launch(void* const* d_in, const int* in_sizes, int n_in,
                              void* d_out, int out_size, void* d_ws, size_t ws_size,
                              hipStream_t stream)
{
    const f32x4* in  = (const f32x4*)d_in[0];
    f32x4*       out = (f32x4*)d_out;
    const int total4 = out_size / 4;  // 17,713,152

    conv_capsules_gather_nt_kernel<<<4096, 256, 0, stream>>>(in, out, total4);
}

// Round 6
// 52.175 us; speedup vs baseline: 1.5623x; 1.5623x over previous
//
#include <hip/hip_runtime.h>

// conv_capsules patch extraction — tile-ordered GATHER + XCD swizzle + NT stores.
// x: [B=8, H=64, W=64, C=16, D=16] f32 -> out: [B, OH=62, OW=62, KH=3, KW=3, C, D]
// out[b,oh,ow,kh,kw,c,d] = x[b,oh+kh,ow+kw,c,d]
//
// Evidence so far:
//   R1 tile-ordered gather, cached writes: 82us (write stream evicts input -> 9x reads)
//   R3/R4 scatter (min traffic 317MB, scattered writes): 60us (5.3 TB/s write eff.)
//   R5 grid-stride gather + NT writes: 82us (no read-locality window -> NT moot)
// This round combines the halves: tile-ordered blocks give each XCD a sliding
// ~192KB input window; NT stores keep the write stream from evicting it.
// Expect reads L2-absorbed: ~317MB HBM at linear-write rate -> ~48us.

typedef float f32x4 __attribute__((ext_vector_type(4)));

constexpr int B  = 8;
constexpr int H  = 64;
constexpr int W  = 64;
constexpr int KH = 3;
constexpr int KW = 3;
constexpr int OH = H - KH + 1;   // 62
constexpr int OW = W - KW + 1;   // 62
constexpr int PIX4  = 64;        // float4 per (c,d) pixel (256 floats = 1KB)
constexpr int TILE4 = KH * KW * PIX4;  // 576 float4 per output tile (9KB)
constexpr int NTILES = B * OH * OW;    // 30752
constexpr int NXCD = 8;

__global__ __launch_bounds__(192) void conv_capsules_gather_nt_tiles_kernel(
    const f32x4* __restrict__ in, f32x4* __restrict__ out)
{
    // Bijective XCD swizzle (NTILES % 8 == 0): each XCD walks a contiguous
    // (b,oh,ow) range in order -> sliding 3-row input window, L2-resident.
    constexpr int CPX = NTILES / NXCD;  // 3844
    const int bid  = blockIdx.x;
    const int tile = (bid % NXCD) * CPX + (bid / NXCD);

    int t = tile;
    const int ow = t % OW; t /= OW;
    const int oh = t % OH;
    const int b  = t / OH;

    const int tid = threadIdx.x;  // 0..191

    f32x4 r0, r1, r2;
    {   // j = tid: pixel p = j>>6 (0..2), lane = j&63
        const int p = tid >> 6, lane = tid & 63;
        const int kh = p / 3, kw = p - kh * 3;   // p<3 -> kh=0
        r0 = in[((b * H + oh + kh) * W + ow + kw) * PIX4 + lane];
    }
    {   // j = tid + 192
        const int j = tid + 192;
        const int p = j >> 6, lane = j & 63;
        const int kh = p / 3, kw = p - kh * 3;
        r1 = in[((b * H + oh + kh) * W + ow + kw) * PIX4 + lane];
    }
    {   // j = tid + 384
        const int j = tid + 384;
        const int p = j >> 6, lane = j & 63;
        const int kh = p / 3, kw = p - kh * 3;
        r2 = in[((b * H + oh + kh) * W + ow + kw) * PIX4 + lane];
    }

    f32x4* o = out + (long)tile * TILE4;
    __builtin_nontemporal_store(r0, &o[tid]);
    __builtin_nontemporal_store(r1, &o[tid + 192]);
    __builtin_nontemporal_store(r2, &o[tid + 384]);
}

extern "C" void kernel_launch(void* const* d_in, const int* in_sizes, int n_in,
                              void* d_out, int out_size, void* d_ws, size_t ws_size,
                              hipStream_t stream)
{
    const f32x4* in  = (const f32x4*)d_in[0];
    f32x4*       out = (f32x4*)d_out;
    conv_capsules_gather_nt_tiles_kernel<<<NTILES, 192, 0, stream>>>(in, out);
}